// Round 3
// baseline (48.217 us; speedup 1.0000x reference)
//
#include <hip/hip_runtime.h>
#include <cstddef>

// out[e,j] = tanh( A[row[e],j] + B[col[e],j] )
// A[n] = W0·(x[n,0:64]+x[n,128:192]) + W1·x[n,64:128]
// B[n] = W0·x[n,64:128] + W1·(x[n,0:64]+x[n,128:192])
// W0 = W[:, 0:64], W1 = W[:, 64:128], W row-major [9][128].

typedef float v4f __attribute__((ext_vector_type(4)));   // clang vector: OK for nontemporal builtins

__device__ __forceinline__ float tanh_fast(float s) {
    s = fminf(fmaxf(s, -30.0f), 30.0f);
    float ex = __expf(2.0f * s);
    return __fdividef(ex - 1.0f, ex + 1.0f);
}

// Kernel 1: per-node projections. 4 lanes (a quad) per node; 64 nodes per 256-thread block.
// x is streamed once -> non-temporal loads (don't pollute L2).
// A/B stores stay cached (kernel 2 gathers from them).
__global__ __launch_bounds__(256) void node_proj_kernel(
    const float* __restrict__ x, const float* __restrict__ W,
    float* __restrict__ A, float* __restrict__ B, int nnodes)
{
    __shared__ float wl[9 * 128];                 // 4.6 KB
    for (int k = threadIdx.x; k < 9 * 128; k += 256) wl[k] = W[k];
    __syncthreads();

    const int quad = threadIdx.x >> 2;            // 0..63: node within block
    const int q    = threadIdx.x & 3;             // lane within quad
    const int n    = blockIdx.x * 64 + quad;
    if (n >= nnodes) return;

    const float* xr = x + (size_t)n * 192;

    float pa[9], pb[9];
#pragma unroll
    for (int j = 0; j < 9; ++j) { pa[j] = 0.0f; pb[j] = 0.0f; }

#pragma unroll
    for (int ii = 0; ii < 4; ++ii) {
        const int c = 16 * ii + 4 * q;            // this lane's float4 channel offset
        v4f x0 = __builtin_nontemporal_load((const v4f*)(xr + c));
        v4f x1 = __builtin_nontemporal_load((const v4f*)(xr + 64 + c));
        v4f x2 = __builtin_nontemporal_load((const v4f*)(xr + 128 + c));
        float ux = x0.x + x2.x, uy = x0.y + x2.y, uz = x0.z + x2.z, uw = x0.w + x2.w;
#pragma unroll
        for (int j = 0; j < 9; ++j) {
            v4f wa = *(const v4f*)(wl + j * 128 + c);
            v4f wb = *(const v4f*)(wl + j * 128 + 64 + c);
            pa[j] = fmaf(wa.x, ux,   pa[j]); pa[j] = fmaf(wa.y, uy,   pa[j]);
            pa[j] = fmaf(wa.z, uz,   pa[j]); pa[j] = fmaf(wa.w, uw,   pa[j]);
            pa[j] = fmaf(wb.x, x1.x, pa[j]); pa[j] = fmaf(wb.y, x1.y, pa[j]);
            pa[j] = fmaf(wb.z, x1.z, pa[j]); pa[j] = fmaf(wb.w, x1.w, pa[j]);
            pb[j] = fmaf(wa.x, x1.x, pb[j]); pb[j] = fmaf(wa.y, x1.y, pb[j]);
            pb[j] = fmaf(wa.z, x1.z, pb[j]); pb[j] = fmaf(wa.w, x1.w, pb[j]);
            pb[j] = fmaf(wb.x, ux,   pb[j]); pb[j] = fmaf(wb.y, uy,   pb[j]);
            pb[j] = fmaf(wb.z, uz,   pb[j]); pb[j] = fmaf(wb.w, uw,   pb[j]);
        }
    }

    // quad butterfly reduce: all 4 lanes end with the full 64-channel sums
#pragma unroll
    for (int j = 0; j < 9; ++j) {
        pa[j] += __shfl_xor(pa[j], 1); pa[j] += __shfl_xor(pa[j], 2);
        pb[j] += __shfl_xor(pb[j], 1); pb[j] += __shfl_xor(pb[j], 2);
    }

    float* Ar = A + (size_t)n * 9;
    float* Br = B + (size_t)n * 9;
    for (int j = q; j < 9; j += 4) { Ar[j] = pa[j]; Br[j] = pb[j]; }
}

// Kernel 2: grid-stride, one thread per output element t = e*9 + j.
// Streaming ei/out traffic marked non-temporal so the 3.6 MB A/B tables
// stay resident in each XCD's 4 MB L2 for the random gathers.
__global__ __launch_bounds__(256) void edge_map_kernel(
    const int* __restrict__ ei, const float* __restrict__ A,
    const float* __restrict__ B, float* __restrict__ out,
    int nedges, int total)
{
    const int stride = gridDim.x * 256;
    for (int t = blockIdx.x * 256 + threadIdx.x; t < total; t += stride) {
        int e = (int)(((long long)t * 954437177LL) >> 33);   // t / 9
        int j = t - e * 9;
        int row = __builtin_nontemporal_load(ei + e);
        int col = __builtin_nontemporal_load(ei + nedges + e);
        float s = A[row * 9 + j] + B[col * 9 + j];
        __builtin_nontemporal_store(tanh_fast(s), out + t);
    }
}

extern "C" void kernel_launch(void* const* d_in, const int* in_sizes, int n_in,
                              void* d_out, int out_size, void* d_ws, size_t ws_size,
                              hipStream_t stream) {
    const float* x  = (const float*)d_in[0];   // [N, 192] fp32
    const float* W  = (const float*)d_in[1];   // [9, 128] fp32
    const int*   ei = (const int*)d_in[2];     // [2, E] int32
    float* out = (float*)d_out;                // [E*9] fp32

    const int nnodes = in_sizes[0] / 192;
    const int nedges = in_sizes[2] / 2;

    float* A = (float*)d_ws;                   // [nnodes*9]
    float* B = A + (size_t)nnodes * 9;         // [nnodes*9]

    const int blocks1 = (nnodes + 63) / 64;
    node_proj_kernel<<<blocks1, 256, 0, stream>>>(x, W, A, B, nnodes);

    const int total   = nedges * 9;
    int blocks2 = (total + 255) / 256;
    if (blocks2 > 2048) blocks2 = 2048;        // grid-stride: amortize WG dispatch, expose MLP
    edge_map_kernel<<<blocks2, 256, 0, stream>>>(ei, A, B, out, nedges, total);
}

// Round 4
// 34.479 us; speedup vs baseline: 1.3984x; 1.3984x over previous
//
#include <hip/hip_runtime.h>
#include <cstddef>

// out[e,j] = tanh( A[row[e],j] + B[col[e],j] )
// A[n] = W0·u + W1·v,  B[n] = W0·v + W1·u,  u = x[n,0:64]+x[n,128:192], v = x[n,64:128]
// Karatsuba: s = (W0+W1)/2·(u+v), d = (W0-W1)/2·(u-v)  =>  A = s+d, B = s-d.
// A/B stored as fp16 (1.8 MB total) so both tables stay L2-resident for the
// random per-edge gathers.

typedef float v4f __attribute__((ext_vector_type(4)));

__device__ __forceinline__ float tanh_fast(float s) {
    // tanh(s) = 1 - 2/(e^{2s}+1);  e^{2s} = 2^(2*log2(e)*s). No clamp: inf/0 limits give +-1.
    float ex = __builtin_amdgcn_exp2f(s * 2.88539008f);
    return fmaf(-2.0f, __builtin_amdgcn_rcpf(ex + 1.0f), 1.0f);
}

// Kernel 1: per-node projections. 4 lanes (a quad) per node; 64 nodes per 256-thread block.
__global__ __launch_bounds__(256) void node_proj_kernel(
    const float* __restrict__ x, const float* __restrict__ W,
    _Float16* __restrict__ A, _Float16* __restrict__ B, int nnodes)
{
    __shared__ float ws[9 * 64];   // (W0+W1)/2
    __shared__ float wd[9 * 64];   // (W0-W1)/2
    for (int k = threadIdx.x; k < 9 * 64; k += 256) {
        int j = k >> 6, c = k & 63;
        float w0 = W[j * 128 + c], w1 = W[j * 128 + 64 + c];
        ws[k] = 0.5f * (w0 + w1);
        wd[k] = 0.5f * (w0 - w1);
    }
    __syncthreads();

    const int quad = threadIdx.x >> 2;            // 0..63: node within block
    const int q    = threadIdx.x & 3;             // lane within quad
    const int n    = blockIdx.x * 64 + quad;
    if (n >= nnodes) return;

    const float* xr = x + (size_t)n * 192;

    float ps[9], pd[9];
#pragma unroll
    for (int j = 0; j < 9; ++j) { ps[j] = 0.0f; pd[j] = 0.0f; }

#pragma unroll
    for (int ii = 0; ii < 4; ++ii) {
        const int c = 16 * ii + 4 * q;            // this lane's float4 channel offset
        v4f x0 = *(const v4f*)(xr + c);
        v4f x1 = *(const v4f*)(xr + 64 + c);
        v4f x2 = *(const v4f*)(xr + 128 + c);
        v4f u = x0 + x2;                          // sum-pool halves
        v4f su = u + x1;                          // u + v
        v4f du = u - x1;                          // u - v
#pragma unroll
        for (int j = 0; j < 9; ++j) {
            v4f a = *(const v4f*)(ws + j * 64 + c);
            v4f b = *(const v4f*)(wd + j * 64 + c);
            ps[j] = fmaf(a.x, su.x, ps[j]); ps[j] = fmaf(a.y, su.y, ps[j]);
            ps[j] = fmaf(a.z, su.z, ps[j]); ps[j] = fmaf(a.w, su.w, ps[j]);
            pd[j] = fmaf(b.x, du.x, pd[j]); pd[j] = fmaf(b.y, du.y, pd[j]);
            pd[j] = fmaf(b.z, du.z, pd[j]); pd[j] = fmaf(b.w, du.w, pd[j]);
        }
    }

    // quad butterfly reduce: all 4 lanes end with full 64-channel sums
#pragma unroll
    for (int j = 0; j < 9; ++j) {
        ps[j] += __shfl_xor(ps[j], 1); ps[j] += __shfl_xor(ps[j], 2);
        pd[j] += __shfl_xor(pd[j], 1); pd[j] += __shfl_xor(pd[j], 2);
    }

    _Float16* Ar = A + (size_t)n * 9;
    _Float16* Br = B + (size_t)n * 9;
    for (int j = q; j < 9; j += 4) {
        Ar[j] = (_Float16)(ps[j] + pd[j]);
        Br[j] = (_Float16)(ps[j] - pd[j]);
    }
}

// Kernel 2: one thread per output element t = e*9 + j. Coalesced out writes;
// A/B gathers are fp16 (tables 1.8 MB -> L2-resident).
__global__ __launch_bounds__(256) void edge_map_kernel(
    const int* __restrict__ ei, const _Float16* __restrict__ A,
    const _Float16* __restrict__ B, float* __restrict__ out,
    int nedges, int total)
{
    int t = blockIdx.x * 256 + threadIdx.x;
    if (t >= total) return;
    int e = (int)(((long long)t * 954437177LL) >> 33);   // t / 9
    int j = t - e * 9;
    int row = ei[e];
    int col = ei[nedges + e];
    float s = (float)A[row * 9 + j] + (float)B[col * 9 + j];
    out[t] = tanh_fast(s);
}

extern "C" void kernel_launch(void* const* d_in, const int* in_sizes, int n_in,
                              void* d_out, int out_size, void* d_ws, size_t ws_size,
                              hipStream_t stream) {
    const float* x  = (const float*)d_in[0];   // [N, 192] fp32
    const float* W  = (const float*)d_in[1];   // [9, 128] fp32
    const int*   ei = (const int*)d_in[2];     // [2, E] int32
    float* out = (float*)d_out;                // [E*9] fp32

    const int nnodes = in_sizes[0] / 192;
    const int nedges = in_sizes[2] / 2;

    _Float16* A = (_Float16*)d_ws;             // [nnodes*9] fp16
    _Float16* B = A + (size_t)nnodes * 9;      // [nnodes*9] fp16

    const int blocks1 = (nnodes + 63) / 64;
    node_proj_kernel<<<blocks1, 256, 0, stream>>>(x, W, A, B, nnodes);

    const int total   = nedges * 9;
    const int blocks2 = (total + 255) / 256;
    edge_map_kernel<<<blocks2, 256, 0, stream>>>(ei, A, B, out, nedges, total);
}

// Round 5
// 32.250 us; speedup vs baseline: 1.4951x; 1.0691x over previous
//
#include <hip/hip_runtime.h>
#include <cstddef>

// out[e,j] = tanh( A[row[e],j] + B[col[e],j] )
// A[n] = W0·u + W1·v,  B[n] = W0·v + W1·u,  u = x[n,0:64]+x[n,128:192], v = x[n,64:128]
// Karatsuba: s = (W0+W1)/2·(u+v), d = (W0-W1)/2·(u-v)  =>  A = s+d, B = s-d.
// A/B tables: fp16, padded to 16 elements (32 B) per node so one edge-side
// gather is a single b128 + u16 load. 3.2 MB total -> L2-resident.

typedef float v4f __attribute__((ext_vector_type(4)));
typedef _Float16 v8h __attribute__((ext_vector_type(8)));

__device__ __forceinline__ float tanh_fast(float s) {
    // tanh(s) = 1 - 2/(e^{2s}+1);  e^{2s} = 2^(2*log2(e)*s). No clamp: inf/0 limits give +-1.
    float ex = __builtin_amdgcn_exp2f(s * 2.88539008f);
    return fmaf(-2.0f, __builtin_amdgcn_rcpf(ex + 1.0f), 1.0f);
}

// Kernel 1: per-node projections. 4 lanes (a quad) per node; 64 nodes per 256-thread block.
__global__ __launch_bounds__(256) void node_proj_kernel(
    const float* __restrict__ x, const float* __restrict__ W,
    _Float16* __restrict__ A, _Float16* __restrict__ B, int nnodes)
{
    __shared__ float ws[9 * 64];   // (W0+W1)/2
    __shared__ float wd[9 * 64];   // (W0-W1)/2
    for (int k = threadIdx.x; k < 9 * 64; k += 256) {
        int j = k >> 6, c = k & 63;
        float w0 = W[j * 128 + c], w1 = W[j * 128 + 64 + c];
        ws[k] = 0.5f * (w0 + w1);
        wd[k] = 0.5f * (w0 - w1);
    }
    __syncthreads();

    const int quad = threadIdx.x >> 2;            // 0..63: node within block
    const int q    = threadIdx.x & 3;             // lane within quad
    const int n    = blockIdx.x * 64 + quad;
    if (n >= nnodes) return;

    const float* xr = x + (size_t)n * 192;

    float ps[9], pd[9];
#pragma unroll
    for (int j = 0; j < 9; ++j) { ps[j] = 0.0f; pd[j] = 0.0f; }

#pragma unroll
    for (int ii = 0; ii < 4; ++ii) {
        const int c = 16 * ii + 4 * q;            // this lane's float4 channel offset
        v4f x0 = *(const v4f*)(xr + c);
        v4f x1 = *(const v4f*)(xr + 64 + c);
        v4f x2 = *(const v4f*)(xr + 128 + c);
        v4f u = x0 + x2;                          // sum-pool halves
        v4f su = u + x1;                          // u + v
        v4f du = u - x1;                          // u - v
#pragma unroll
        for (int j = 0; j < 9; ++j) {
            v4f a = *(const v4f*)(ws + j * 64 + c);
            v4f b = *(const v4f*)(wd + j * 64 + c);
            ps[j] = fmaf(a.x, su.x, ps[j]); ps[j] = fmaf(a.y, su.y, ps[j]);
            ps[j] = fmaf(a.z, su.z, ps[j]); ps[j] = fmaf(a.w, su.w, ps[j]);
            pd[j] = fmaf(b.x, du.x, pd[j]); pd[j] = fmaf(b.y, du.y, pd[j]);
            pd[j] = fmaf(b.z, du.z, pd[j]); pd[j] = fmaf(b.w, du.w, pd[j]);
        }
    }

    // quad butterfly reduce: all 4 lanes end with full 64-channel sums
#pragma unroll
    for (int j = 0; j < 9; ++j) {
        ps[j] += __shfl_xor(ps[j], 1); ps[j] += __shfl_xor(ps[j], 2);
        pd[j] += __shfl_xor(pd[j], 1); pd[j] += __shfl_xor(pd[j], 2);
    }

    _Float16* Ar = A + (size_t)n * 16;            // padded 32B records
    _Float16* Br = B + (size_t)n * 16;
    for (int j = q; j < 9; j += 4) {
        Ar[j] = (_Float16)(ps[j] + pd[j]);
        Br[j] = (_Float16)(ps[j] - pd[j]);
    }
}

// Kernel 2: ONE thread per edge. Padded 32B gathers (b128 + u16), 9 tanh in
// registers, then LDS transpose so the 36B/edge output leaves as fully
// coalesced dword streams. 800000 edges = 3125 exact blocks of 256.
__global__ __launch_bounds__(256) void edge_map_kernel(
    const int* __restrict__ ei, const _Float16* __restrict__ A,
    const _Float16* __restrict__ B, float* __restrict__ out, int nedges)
{
    __shared__ float so[256 * 9];                 // 9 KB
    const int e0 = blockIdx.x * 256;
    const int e  = e0 + threadIdx.x;
    const int cnt = min(256, nedges - e0);

    if (e < nedges) {
        int row = ei[e];
        int col = ei[nedges + e];
        const _Float16* Ar = A + (size_t)row * 16;
        const _Float16* Br = B + (size_t)col * 16;
        v8h a8 = *(const v8h*)Ar;  _Float16 a8e = Ar[8];
        v8h b8 = *(const v8h*)Br;  _Float16 b8e = Br[8];
        float* sl = so + threadIdx.x * 9;         // stride 9: conflict-free
#pragma unroll
        for (int j = 0; j < 8; ++j)
            sl[j] = tanh_fast((float)a8[j] + (float)b8[j]);
        sl[8] = tanh_fast((float)a8e + (float)b8e);
    }
    __syncthreads();

    float* ob = out + (size_t)e0 * 9;
    const int tot = cnt * 9;
    for (int k = threadIdx.x; k < tot; k += 256)  // coalesced dword stores
        ob[k] = so[k];
}

extern "C" void kernel_launch(void* const* d_in, const int* in_sizes, int n_in,
                              void* d_out, int out_size, void* d_ws, size_t ws_size,
                              hipStream_t stream) {
    const float* x  = (const float*)d_in[0];   // [N, 192] fp32
    const float* W  = (const float*)d_in[1];   // [9, 128] fp32
    const int*   ei = (const int*)d_in[2];     // [2, E] int32
    float* out = (float*)d_out;                // [E*9] fp32

    const int nnodes = in_sizes[0] / 192;
    const int nedges = in_sizes[2] / 2;

    _Float16* A = (_Float16*)d_ws;             // [nnodes*16] fp16 padded records
    _Float16* B = A + (size_t)nnodes * 16;     // [nnodes*16]

    const int blocks1 = (nnodes + 63) / 64;
    node_proj_kernel<<<blocks1, 256, 0, stream>>>(x, W, A, B, nnodes);

    const int blocks2 = (nedges + 255) / 256;
    edge_map_kernel<<<blocks2, 256, 0, stream>>>(ei, A, B, out, nedges);
}

// Round 6
// 31.204 us; speedup vs baseline: 1.5452x; 1.0335x over previous
//
#include <hip/hip_runtime.h>
#include <cstddef>

// out[e,j] = tanh( A[row[e],j] + B[col[e],j] )
// A[n] = W0·u + W1·v,  B[n] = W0·v + W1·u,  u = x[n,0:64]+x[n,128:192], v = x[n,64:128]
// Karatsuba: s = (W0+W1)/2·(u+v), d = (W0-W1)/2·(u-v)  =>  A = s+d, B = s-d.
// A/B tables: fp16, padded to 16 elements (32 B) per node. Kernel 2 gathers each
// record with FOUR lanes x 8 B (quad-cooperative) -> one distinct cache line per
// record, 2 line-misses per edge instead of 4.

typedef float v4f __attribute__((ext_vector_type(4)));
typedef _Float16 v4h __attribute__((ext_vector_type(4)));

__device__ __forceinline__ float tanh_fast(float s) {
    // tanh(s) = 1 - 2/(e^{2s}+1);  e^{2s} = 2^(2*log2(e)*s). No clamp: inf/0 limits give +-1.
    float ex = __builtin_amdgcn_exp2f(s * 2.88539008f);
    return fmaf(-2.0f, __builtin_amdgcn_rcpf(ex + 1.0f), 1.0f);
}

// Kernel 1: per-node projections. 4 lanes (a quad) per node; 64 nodes per 256-thread block.
__global__ __launch_bounds__(256) void node_proj_kernel(
    const float* __restrict__ x, const float* __restrict__ W,
    _Float16* __restrict__ A, _Float16* __restrict__ B, int nnodes)
{
    __shared__ float ws[9 * 64];   // (W0+W1)/2
    __shared__ float wd[9 * 64];   // (W0-W1)/2
    for (int k = threadIdx.x; k < 9 * 64; k += 256) {
        int j = k >> 6, c = k & 63;
        float w0 = W[j * 128 + c], w1 = W[j * 128 + 64 + c];
        ws[k] = 0.5f * (w0 + w1);
        wd[k] = 0.5f * (w0 - w1);
    }
    __syncthreads();

    const int quad = threadIdx.x >> 2;            // 0..63: node within block
    const int q    = threadIdx.x & 3;             // lane within quad
    const int n    = blockIdx.x * 64 + quad;
    if (n >= nnodes) return;

    const float* xr = x + (size_t)n * 192;

    float ps[9], pd[9];
#pragma unroll
    for (int j = 0; j < 9; ++j) { ps[j] = 0.0f; pd[j] = 0.0f; }

#pragma unroll
    for (int ii = 0; ii < 4; ++ii) {
        const int c = 16 * ii + 4 * q;            // this lane's float4 channel offset
        v4f x0 = *(const v4f*)(xr + c);
        v4f x1 = *(const v4f*)(xr + 64 + c);
        v4f x2 = *(const v4f*)(xr + 128 + c);
        v4f u = x0 + x2;                          // sum-pool halves
        v4f su = u + x1;                          // u + v
        v4f du = u - x1;                          // u - v
#pragma unroll
        for (int j = 0; j < 9; ++j) {
            v4f a = *(const v4f*)(ws + j * 64 + c);
            v4f b = *(const v4f*)(wd + j * 64 + c);
            ps[j] = fmaf(a.x, su.x, ps[j]); ps[j] = fmaf(a.y, su.y, ps[j]);
            ps[j] = fmaf(a.z, su.z, ps[j]); ps[j] = fmaf(a.w, su.w, ps[j]);
            pd[j] = fmaf(b.x, du.x, pd[j]); pd[j] = fmaf(b.y, du.y, pd[j]);
            pd[j] = fmaf(b.z, du.z, pd[j]); pd[j] = fmaf(b.w, du.w, pd[j]);
        }
    }

    // quad butterfly reduce: all 4 lanes end with full 64-channel sums
#pragma unroll
    for (int j = 0; j < 9; ++j) {
        ps[j] += __shfl_xor(ps[j], 1); ps[j] += __shfl_xor(ps[j], 2);
        pd[j] += __shfl_xor(pd[j], 1); pd[j] += __shfl_xor(pd[j], 2);
    }

    _Float16* Ar = A + (size_t)n * 16;            // padded 32B records
    _Float16* Br = B + (size_t)n * 16;
    for (int j = q; j < 9; j += 4) {
        Ar[j] = (_Float16)(ps[j] + pd[j]);
        Br[j] = (_Float16)(ps[j] - pd[j]);
    }
}

// Kernel 2: FOUR lanes (a quad) per edge. Lane q loads bytes [8q, 8q+8) of the
// 32B A[row] and B[col] records -> the quad's 4 lane-requests per record merge
// into ONE cache line: 2 distinct-line requests per edge (was 4).
// Lane q then owns outputs j = 4q..4q+3 with no cross-lane exchange.
// LDS transpose keeps the 36 B/edge output as coalesced float4 streams.
__global__ __launch_bounds__(256) void edge_map_kernel(
    const int* __restrict__ ei, const _Float16* __restrict__ A,
    const _Float16* __restrict__ B, float* __restrict__ out, int nedges)
{
    __shared__ float so[64 * 9];                  // 2.25 KB
    const int quad = threadIdx.x >> 2;            // 0..63: edge slot in block
    const int q    = threadIdx.x & 3;             // lane within quad
    const int e0   = blockIdx.x * 64;
    const int e    = e0 + quad;

    if (q < 3 && e < nedges) {                    // q==3 covers only pad -> masked off
        int row = ei[e];                          // 4-lane same-address: broadcast
        int col = ei[nedges + e];
        v4h a2 = *(const v4h*)(A + (size_t)row * 16 + 4 * q);
        v4h b2 = *(const v4h*)(B + (size_t)col * 16 + 4 * q);
        float* sl = so + quad * 9 + 4 * q;
#pragma unroll
        for (int i = 0; i < 4; ++i) {
            if (4 * q + i < 9)                    // q<2: all 4; q==2: only i==0
                sl[i] = tanh_fast((float)a2[i] + (float)b2[i]);
        }
    }
    __syncthreads();

    const int nval = (min(64, nedges - e0)) * 9;  // 576 for full blocks
    float* ob = out + (size_t)e0 * 9;
    int k4 = threadIdx.x * 4;
    if (k4 < nval) {
        if (k4 + 4 <= nval) {
            *(v4f*)(ob + k4) = *(const v4f*)(so + k4);   // 16B-aligned, coalesced
        } else {
            for (int m = k4; m < nval; ++m) ob[m] = so[m];
        }
    }
}

extern "C" void kernel_launch(void* const* d_in, const int* in_sizes, int n_in,
                              void* d_out, int out_size, void* d_ws, size_t ws_size,
                              hipStream_t stream) {
    const float* x  = (const float*)d_in[0];   // [N, 192] fp32
    const float* W  = (const float*)d_in[1];   // [9, 128] fp32
    const int*   ei = (const int*)d_in[2];     // [2, E] int32
    float* out = (float*)d_out;                // [E*9] fp32

    const int nnodes = in_sizes[0] / 192;
    const int nedges = in_sizes[2] / 2;

    _Float16* A = (_Float16*)d_ws;             // [nnodes*16] fp16 padded records
    _Float16* B = A + (size_t)nnodes * 16;     // [nnodes*16]

    const int blocks1 = (nnodes + 63) / 64;
    node_proj_kernel<<<blocks1, 256, 0, stream>>>(x, W, A, B, nnodes);

    const int blocks2 = (nedges + 63) / 64;    // 64 edges per 256-thread block
    edge_map_kernel<<<blocks2, 256, 0, stream>>>(ei, A, B, out, nedges);
}